// Round 3
// baseline (487.620 us; speedup 1.0000x reference)
//
#include <hip/hip_runtime.h>
#include <hip/hip_bf16.h>
#include <math.h>

namespace {

constexpr int L_SEQ  = 2048;
constexpr int DPROJ  = 2568;
constexpr int OFF_X  = 1024;
constexpr int OFF_B  = 2048;
constexpr int OFF_C  = 2304;
constexpr int OFF_DT = 2560;
constexpr int OFF_LAM= 2564;
constexpr int SCHUNK = 128;
constexpr int NCH    = L_SEQ / SCHUNK;  // 16

// ---------------------------------------------------------------------------
// Generic C[M,Nn] = A[M,K] * B[Nn,K]^T (+bias), f32, LDS-tiled.
// ---------------------------------------------------------------------------
template<int BM, int BN, int BK, int TM, int TN>
__global__ __launch_bounds__(256)
void gemm_abt(const float* __restrict__ A, int lda,
              const float* __restrict__ B, int ldb,
              const float* __restrict__ bias,
              float* __restrict__ C, int ldc,
              int M, int Nn, int K)
{
  constexpr int NTX = BN / TN;
  constexpr int NTY = BM / TM;
  static_assert(NTX * NTY == 256, "need 256 threads");
  __shared__ float As[BK][BM + 4];
  __shared__ float Bs[BK][BN + 4];
  const int tid = threadIdx.x;
  const int tx  = tid % NTX;
  const int ty  = tid / NTX;
  const int bm  = blockIdx.x * BM;
  const int bn  = blockIdx.y * BN;

  float acc[TM][TN];
#pragma unroll
  for (int i = 0; i < TM; ++i)
#pragma unroll
    for (int j = 0; j < TN; ++j) acc[i][j] = 0.f;

  for (int k0 = 0; k0 < K; k0 += BK) {
    for (int idx = tid; idx < (BM * BK) / 4; idx += 256) {
      int row = idx / (BK / 4);
      int kc  = (idx % (BK / 4)) * 4;
      float4 v = make_float4(0.f, 0.f, 0.f, 0.f);
      int gr = bm + row;
      if (gr < M) v = *reinterpret_cast<const float4*>(A + (size_t)gr * lda + k0 + kc);
      As[kc + 0][row] = v.x; As[kc + 1][row] = v.y;
      As[kc + 2][row] = v.z; As[kc + 3][row] = v.w;
    }
    for (int idx = tid; idx < (BN * BK) / 4; idx += 256) {
      int row = idx / (BK / 4);
      int kc  = (idx % (BK / 4)) * 4;
      float4 v = make_float4(0.f, 0.f, 0.f, 0.f);
      int gr = bn + row;
      if (gr < Nn) v = *reinterpret_cast<const float4*>(B + (size_t)gr * ldb + k0 + kc);
      Bs[kc + 0][row] = v.x; Bs[kc + 1][row] = v.y;
      Bs[kc + 2][row] = v.z; Bs[kc + 3][row] = v.w;
    }
    __syncthreads();
#pragma unroll
    for (int k = 0; k < BK; ++k) {
      float ra[TM], rb[TN];
#pragma unroll
      for (int i = 0; i < TM; ++i) ra[i] = As[k][ty * TM + i];
#pragma unroll
      for (int j = 0; j < TN; ++j) rb[j] = Bs[k][tx * TN + j];
#pragma unroll
      for (int i = 0; i < TM; ++i)
#pragma unroll
        for (int j = 0; j < TN; ++j)
          acc[i][j] = fmaf(ra[i], rb[j], acc[i][j]);
    }
    __syncthreads();
  }

#pragma unroll
  for (int i = 0; i < TM; ++i) {
    int gm = bm + ty * TM + i;
    if (gm >= M) continue;
#pragma unroll
    for (int j = 0; j < TN; ++j) {
      int gn = bn + tx * TN + j;
      if (gn < Nn) {
        float v = acc[i][j];
        if (bias) v += bias[gn];
        C[(size_t)gm * ldc + gn] = v;
      }
    }
  }
}

// ---------------------------------------------------------------------------
// dt = softplus, lam = sigmoid, alpha = exp(dt*A), plus u_eff coefficients.
// ---------------------------------------------------------------------------
__global__ __launch_bounds__(256)
void dtlam_kernel(const float* __restrict__ proj, const float* __restrict__ A_log,
                  float* __restrict__ dtg, float* __restrict__ alphag,
                  float* __restrict__ c0g, float* __restrict__ c1g)
{
  int idx = blockIdx.x * 256 + threadIdx.x;      // L*G = 8192
  if (idx >= L_SEQ * 4) return;
  int l = idx >> 2, g = idx & 3;
  float x  = proj[(size_t)l * DPROJ + OFF_DT + g];
  float dt = (x > 20.f) ? x : log1pf(expf(x));
  float zl = proj[(size_t)l * DPROJ + OFF_LAM + g];
  float lam = 1.f / (1.f + expf(-zl));
  float Ag  = -expf(A_log[g]);
  float al  = expf(dt * Ag);
  dtg[idx]    = dt;
  alphag[idx] = al;
  c0g[idx]    = 1.f - lam;
  c1g[idx]    = lam * al;
}

// ---------------------------------------------------------------------------
// f64 inclusive cumsum of dt over L, per group.  grid=4 (g), block=256.
// ---------------------------------------------------------------------------
__global__ __launch_bounds__(256)
void cumsum_dt_kernel(const float* __restrict__ dtg, float* __restrict__ cumdt)
{
  const int g = blockIdx.x;
  const int t = threadIdx.x;
  constexpr int PER = L_SEQ / 256;  // 8
  __shared__ double ps[256];
  float loc[PER];
  double s = 0.0;
  int l0 = t * PER;
  for (int i = 0; i < PER; ++i) {
    loc[i] = dtg[(l0 + i) * 4 + g];
    s += (double)loc[i];
  }
  ps[t] = s;
  __syncthreads();
  for (int off = 1; off < 256; off <<= 1) {
    double v = (t >= off) ? ps[t - off] : 0.0;
    __syncthreads();
    ps[t] += v;
    __syncthreads();
  }
  double c = ps[t] - s;  // exclusive prefix
  for (int i = 0; i < PER; ++i) {
    c += (double)loc[i];
    cumdt[(l0 + i) * 4 + g] = (float)c;
  }
}

// ---------------------------------------------------------------------------
// Per-token: silu(xp) -> xs ; rms+bias+rope for B/C (group level).
// grid = L, block = 256 (wave w handles group g=w; lane = e in [0,64)).
// ---------------------------------------------------------------------------
__global__ __launch_bounds__(256)
void pertoken_kernel(const float* __restrict__ proj,
                     const float* __restrict__ cumdt,
                     const float* __restrict__ theta_log,
                     const float* __restrict__ norm_B_w,
                     const float* __restrict__ norm_C_w,
                     const float* __restrict__ bias_B,
                     const float* __restrict__ bias_C,
                     float* __restrict__ xs,
                     float* __restrict__ Brot,
                     float* __restrict__ Crot)
{
  const int l = blockIdx.x;
  const int t = threadIdx.x;
  const size_t prow = (size_t)l * DPROJ;

  for (int i = t; i < 1024; i += 256) {
    float x = proj[prow + OFF_X + i];
    xs[(size_t)l * 1024 + i] = x / (1.f + expf(-x));
  }

  const int g = t >> 6;
  const int e = t & 63;
  float bv = proj[prow + OFF_B + t];
  float cv = proj[prow + OFF_C + t];
  float ssb = bv * bv, ssc = cv * cv;
#pragma unroll
  for (int m = 1; m <= 32; m <<= 1) {
    ssb += __shfl_xor(ssb, m, 64);
    ssc += __shfl_xor(ssc, m, 64);
  }
  float nb = bv * rsqrtf(ssb * (1.f / 64.f) + 1e-5f) * norm_B_w[e] + bias_B[t];
  float nc = cv * rsqrtf(ssc * (1.f / 64.f) + 1e-5f) * norm_C_w[e] + bias_C[t];

  float ang = expf(theta_log[g * 16 + (e >> 2)]) * cumdt[l * 4 + g];
  float ca, sa;
  sincosf(ang, &sa, &ca);   // sincosf writes SIN to 1st ptr, COS to 2nd
  float nb2 = __shfl_xor(nb, 2, 64);
  float nc2 = __shfl_xor(nc, 2, 64);
  bool isre = ((e >> 1) & 1) == 0;
  float Bo, Co;
  if (isre) {         // holds re; partner is im
    Bo = nb * ca + nb2 * sa;   // theta = -ang
    Co = nc * ca - nc2 * sa;   // theta = +ang
  } else {            // holds im; partner is re
    Bo = nb * ca - nb2 * sa;
    Co = nc * ca + nc2 * sa;
  }
  Brot[(size_t)l * 256 + t] = Bo;
  Crot[(size_t)l * 256 + t] = Co;
}

// ---------------------------------------------------------------------------
// Scan pass A: per-chunk recurrence from zero -> h_last[c,h,p,n].
// grid = (NCH, H, 4), block = 512. thread: n = tid&31, p = pt*16 + tid>>5.
// ---------------------------------------------------------------------------
__global__ __launch_bounds__(512)
void scan_passA(const float* __restrict__ Brot, const float* __restrict__ xup,
                const float* __restrict__ dtg, const float* __restrict__ alphag,
                const float* __restrict__ c0g, const float* __restrict__ c1g,
                float* __restrict__ hlast)
{
  const int c = blockIdx.x, h = blockIdx.y, pt = blockIdx.z;
  const int g = h >> 2;
  const int tid = threadIdx.x;
  const int n = tid & 31;
  const int p = pt * 16 + (tid >> 5);
  const int l0 = c * SCHUNK;

  float Hs = 0.f, uprev = 0.f;
  if (l0 > 0) {
    int lm = l0 - 1;
    float2 Bv = *reinterpret_cast<const float2*>(&Brot[(size_t)lm * 256 + g * 64 + 2 * n]);
    float2 Xv = *reinterpret_cast<const float2*>(&xup[((size_t)lm * 16 + h) * 128 + 2 * p]);
    uprev = dtg[lm * 4 + g] * (Bv.x * Xv.x + Bv.y * Xv.y);
  }
#pragma unroll 2
  for (int l = l0; l < l0 + SCHUNK; ++l) {
    float2 Bv = *reinterpret_cast<const float2*>(&Brot[(size_t)l * 256 + g * 64 + 2 * n]);
    float2 Xv = *reinterpret_cast<const float2*>(&xup[((size_t)l * 16 + h) * 128 + 2 * p]);
    float dt = dtg[l * 4 + g], al = alphag[l * 4 + g];
    float c0 = c0g[l * 4 + g], c1 = c1g[l * 4 + g];
    float uin  = dt * (Bv.x * Xv.x + Bv.y * Xv.y);
    float ueff = c0 * uin + c1 * uprev;
    Hs = al * Hs + ueff;
    uprev = uin;
  }
  hlast[(((size_t)c * 16 + h) * 64 + p) * 32 + n] = Hs;
}

// ---------------------------------------------------------------------------
// Scan pass B: cross-chunk combine -> h_states (state entering each chunk).
// ---------------------------------------------------------------------------
__global__ __launch_bounds__(256)
void scan_passB(const float* __restrict__ hlast, const float* __restrict__ cumdt,
                const float* __restrict__ A_log, float* __restrict__ hstates)
{
  int idx = blockIdx.x * 256 + threadIdx.x;   // H * P * N = 32768
  int h = idx >> 11;
  int rem = idx & 2047;                       // p*32 + n
  int g = h >> 2;
  float Ag = -expf(A_log[g]);
  float s = 0.f;
  for (int c = 0; c < NCH; ++c) {
    hstates[((size_t)c * 16 + h) * 2048 + rem] = s;
    float sd = cumdt[(c * SCHUNK + SCHUNK - 1) * 4 + g]
             - (c > 0 ? cumdt[(c * SCHUNK - 1) * 4 + g] : 0.f);
    float dec = expf(Ag * sd);
    s = s * dec + hlast[((size_t)c * 16 + h) * 2048 + rem];
  }
}

// ---------------------------------------------------------------------------
// Scan pass C: rescan from h_states, y[l,h,2p+r] = sum_n H[l,n,p]*C[l,n,r].
// ---------------------------------------------------------------------------
__global__ __launch_bounds__(512)
void scan_passC(const float* __restrict__ Brot, const float* __restrict__ Crot,
                const float* __restrict__ xup,
                const float* __restrict__ dtg, const float* __restrict__ alphag,
                const float* __restrict__ c0g, const float* __restrict__ c1g,
                const float* __restrict__ hstates, float* __restrict__ y128)
{
  const int c = blockIdx.x, h = blockIdx.y, pt = blockIdx.z;
  const int g = h >> 2;
  const int tid = threadIdx.x;
  const int n = tid & 31;
  const int p = pt * 16 + (tid >> 5);
  const int l0 = c * SCHUNK;

  float Hs = hstates[(((size_t)c * 16 + h) * 64 + p) * 32 + n];
  float uprev = 0.f;
  if (l0 > 0) {
    int lm = l0 - 1;
    float2 Bv = *reinterpret_cast<const float2*>(&Brot[(size_t)lm * 256 + g * 64 + 2 * n]);
    float2 Xv = *reinterpret_cast<const float2*>(&xup[((size_t)lm * 16 + h) * 128 + 2 * p]);
    uprev = dtg[lm * 4 + g] * (Bv.x * Xv.x + Bv.y * Xv.y);
  }
#pragma unroll 2
  for (int l = l0; l < l0 + SCHUNK; ++l) {
    float2 Bv = *reinterpret_cast<const float2*>(&Brot[(size_t)l * 256 + g * 64 + 2 * n]);
    float2 Xv = *reinterpret_cast<const float2*>(&xup[((size_t)l * 16 + h) * 128 + 2 * p]);
    float dt = dtg[l * 4 + g], al = alphag[l * 4 + g];
    float c0 = c0g[l * 4 + g], c1 = c1g[l * 4 + g];
    float uin  = dt * (Bv.x * Xv.x + Bv.y * Xv.y);
    float ueff = c0 * uin + c1 * uprev;
    Hs = al * Hs + ueff;
    uprev = uin;

    float2 Cv = *reinterpret_cast<const float2*>(&Crot[(size_t)l * 256 + g * 64 + 2 * n]);
    float y0 = Hs * Cv.x;
    float y1 = Hs * Cv.y;
#pragma unroll
    for (int m = 1; m <= 16; m <<= 1) {
      y0 += __shfl_xor(y0, m, 64);
      y1 += __shfl_xor(y1, m, 64);
    }
    if (n == 0) {
      *reinterpret_cast<float2*>(&y128[((size_t)l * 16 + h) * 128 + 2 * p]) =
          make_float2(y0, y1);
    }
  }
}

// ---------------------------------------------------------------------------
// Fuse: yg = (yd + D[h]*xs) * silu(z), written in place into proj's z region.
// ---------------------------------------------------------------------------
__global__ __launch_bounds__(256)
void fuse_gate_kernel(const float* __restrict__ yd, const float* __restrict__ xs,
                      const float* __restrict__ Dv, float* __restrict__ proj)
{
  int idx = blockIdx.x * 256 + threadIdx.x;   // L * 1024
  int l = idx >> 10, m = idx & 1023, h = m >> 6;
  float v = yd[((size_t)l * 16 + h) * 64 + (m & 63)] + Dv[h] * xs[idx];
  float z = proj[(size_t)l * DPROJ + m];
  float sz = z / (1.f + expf(-z));
  proj[(size_t)l * DPROJ + m] = v * sz;
}

}  // namespace

extern "C" void kernel_launch(void* const* d_in, const int* in_sizes, int n_in,
                              void* d_out, int out_size, void* d_ws, size_t ws_size,
                              hipStream_t stream)
{
  const float* u         = (const float*)d_in[0];
  const float* W_in      = (const float*)d_in[1];
  const float* b_in      = (const float*)d_in[2];
  const float* W_xup     = (const float*)d_in[3];
  const float* W_ydown   = (const float*)d_in[4];
  const float* A_log     = (const float*)d_in[5];
  const float* theta_log = (const float*)d_in[6];
  const float* Dvec      = (const float*)d_in[7];
  const float* norm_B_w  = (const float*)d_in[8];
  const float* norm_C_w  = (const float*)d_in[9];
  const float* bias_B    = (const float*)d_in[10];
  const float* bias_C    = (const float*)d_in[11];
  const float* W_out     = (const float*)d_in[12];
  float* out = (float*)d_out;

  // Workspace carve (f32 counts)
  float* proj    = (float*)d_ws;                    // 2048*2568
  float* xs      = proj    + (size_t)L_SEQ * DPROJ; // 2048*1024
  float* dtg     = xs      + (size_t)L_SEQ * 1024;  // 2048*4
  float* alphag  = dtg     + L_SEQ * 4;
  float* c0g     = alphag  + L_SEQ * 4;
  float* c1g     = c0g     + L_SEQ * 4;
  float* cumdt   = c1g     + L_SEQ * 4;
  float* Brot    = cumdt   + L_SEQ * 4;             // 2048*256
  float* Crot    = Brot    + (size_t)L_SEQ * 256;
  float* xup     = Crot    + (size_t)L_SEQ * 256;   // 32768*128
  float* hlast   = xup     + (size_t)32768 * 128;   // NCH*16*2048
  float* hstates = hlast   + (size_t)NCH * 16 * 2048;
  float* y128    = hstates + (size_t)NCH * 16 * 2048;   // 32768*128
  float* yd      = y128    + (size_t)32768 * 128;       // 32768*64

  // 1. proj = u @ W_in^T + b_in        (2048 x 2568, K=512)
  gemm_abt<128, 128, 8, 8, 8><<<dim3(16, 21), 256, 0, stream>>>(
      u, 512, W_in, 512, b_in, proj, DPROJ, L_SEQ, DPROJ, 512);

  // 2. dt / lam / alpha coefficients
  dtlam_kernel<<<dim3(32), 256, 0, stream>>>(proj, A_log, dtg, alphag, c0g, c1g);

  // 3. f64 cumsum of dt per group
  cumsum_dt_kernel<<<dim3(4), 256, 0, stream>>>(dtg, cumdt);

  // 4. per-token: silu(xp), rms+bias+rope -> Brot/Crot
  pertoken_kernel<<<dim3(L_SEQ), 256, 0, stream>>>(
      proj, cumdt, theta_log, norm_B_w, norm_C_w, bias_B, bias_C, xs, Brot, Crot);

  // 5. x_up = xs(32768x64) @ W_xup^T(64x128)
  gemm_abt<128, 128, 8, 8, 8><<<dim3(256, 1), 256, 0, stream>>>(
      xs, 64, W_xup, 64, nullptr, xup, 128, 32768, 128, 64);

  // 6-8. chunked scan
  scan_passA<<<dim3(NCH, 16, 4), 512, 0, stream>>>(
      Brot, xup, dtg, alphag, c0g, c1g, hlast);
  scan_passB<<<dim3(128), 256, 0, stream>>>(hlast, cumdt, A_log, hstates);
  scan_passC<<<dim3(NCH, 16, 4), 512, 0, stream>>>(
      Brot, Crot, xup, dtg, alphag, c0g, c1g, hstates, y128);

  // 9. yd = y128(32768x128) @ W_ydown^T(128x64)
  gemm_abt<128, 64, 8, 8, 4><<<dim3(256, 1), 256, 0, stream>>>(
      y128, 128, W_ydown, 128, nullptr, yd, 64, 32768, 64, 128);

  // 10. gate: yg = (yd + D*xs) * silu(z), in place into proj[:, 0:1024]
  fuse_gate_kernel<<<dim3(8192), 256, 0, stream>>>(yd, xs, Dvec, proj);

  // 11. out = yg(2048x1024) @ W_out^T(1024->512)
  gemm_abt<64, 64, 8, 4, 4><<<dim3(32, 8), 256, 0, stream>>>(
      proj, DPROJ, W_out, 1024, nullptr, out, 512, L_SEQ, 512, 1024);
}

// Round 4
// 364.573 us; speedup vs baseline: 1.3375x; 1.3375x over previous
//
#include <hip/hip_runtime.h>
#include <hip/hip_bf16.h>
#include <math.h>

namespace {

constexpr int L_SEQ  = 2048;
constexpr int DPROJ  = 2568;
constexpr int OFF_X  = 1024;
constexpr int OFF_B  = 2048;
constexpr int OFF_C  = 2304;
constexpr int OFF_DT = 2560;
constexpr int OFF_LAM= 2564;
constexpr int SCHUNK = 32;
constexpr int NCH    = L_SEQ / SCHUNK;  // 64

// ---------------------------------------------------------------------------
// Generic C[M,Nn] = A[M,K] * B[Nn,K]^T (+bias), f32, LDS-tiled.
// ---------------------------------------------------------------------------
template<int BM, int BN, int BK, int TM, int TN>
__global__ __launch_bounds__(256)
void gemm_abt(const float* __restrict__ A, int lda,
              const float* __restrict__ B, int ldb,
              const float* __restrict__ bias,
              float* __restrict__ C, int ldc,
              int M, int Nn, int K)
{
  constexpr int NTX = BN / TN;
  constexpr int NTY = BM / TM;
  static_assert(NTX * NTY == 256, "need 256 threads");
  __shared__ float As[BK][BM + 4];
  __shared__ float Bs[BK][BN + 4];
  const int tid = threadIdx.x;
  const int tx  = tid % NTX;
  const int ty  = tid / NTX;
  const int bm  = blockIdx.x * BM;
  const int bn  = blockIdx.y * BN;

  float acc[TM][TN];
#pragma unroll
  for (int i = 0; i < TM; ++i)
#pragma unroll
    for (int j = 0; j < TN; ++j) acc[i][j] = 0.f;

  for (int k0 = 0; k0 < K; k0 += BK) {
    for (int idx = tid; idx < (BM * BK) / 4; idx += 256) {
      int row = idx / (BK / 4);
      int kc  = (idx % (BK / 4)) * 4;
      float4 v = make_float4(0.f, 0.f, 0.f, 0.f);
      int gr = bm + row;
      if (gr < M) v = *reinterpret_cast<const float4*>(A + (size_t)gr * lda + k0 + kc);
      As[kc + 0][row] = v.x; As[kc + 1][row] = v.y;
      As[kc + 2][row] = v.z; As[kc + 3][row] = v.w;
    }
    for (int idx = tid; idx < (BN * BK) / 4; idx += 256) {
      int row = idx / (BK / 4);
      int kc  = (idx % (BK / 4)) * 4;
      float4 v = make_float4(0.f, 0.f, 0.f, 0.f);
      int gr = bn + row;
      if (gr < Nn) v = *reinterpret_cast<const float4*>(B + (size_t)gr * ldb + k0 + kc);
      Bs[kc + 0][row] = v.x; Bs[kc + 1][row] = v.y;
      Bs[kc + 2][row] = v.z; Bs[kc + 3][row] = v.w;
    }
    __syncthreads();
#pragma unroll
    for (int k = 0; k < BK; ++k) {
      float ra[TM], rb[TN];
#pragma unroll
      for (int i = 0; i < TM; ++i) ra[i] = As[k][ty * TM + i];
#pragma unroll
      for (int j = 0; j < TN; ++j) rb[j] = Bs[k][tx * TN + j];
#pragma unroll
      for (int i = 0; i < TM; ++i)
#pragma unroll
        for (int j = 0; j < TN; ++j)
          acc[i][j] = fmaf(ra[i], rb[j], acc[i][j]);
    }
    __syncthreads();
  }

#pragma unroll
  for (int i = 0; i < TM; ++i) {
    int gm = bm + ty * TM + i;
    if (gm >= M) continue;
#pragma unroll
    for (int j = 0; j < TN; ++j) {
      int gn = bn + tx * TN + j;
      if (gn < Nn) {
        float v = acc[i][j];
        if (bias) v += bias[gn];
        C[(size_t)gm * ldc + gn] = v;
      }
    }
  }
}

// ---------------------------------------------------------------------------
// dt = softplus, lam = sigmoid, alpha = exp(dt*A), plus u_eff coefficients.
// ---------------------------------------------------------------------------
__global__ __launch_bounds__(256)
void dtlam_kernel(const float* __restrict__ proj, const float* __restrict__ A_log,
                  float* __restrict__ dtg, float* __restrict__ alphag,
                  float* __restrict__ c0g, float* __restrict__ c1g)
{
  int idx = blockIdx.x * 256 + threadIdx.x;      // L*G = 8192
  if (idx >= L_SEQ * 4) return;
  int l = idx >> 2, g = idx & 3;
  float x  = proj[(size_t)l * DPROJ + OFF_DT + g];
  float dt = (x > 20.f) ? x : log1pf(expf(x));
  float zl = proj[(size_t)l * DPROJ + OFF_LAM + g];
  float lam = 1.f / (1.f + expf(-zl));
  float Ag  = -expf(A_log[g]);
  float al  = expf(dt * Ag);
  dtg[idx]    = dt;
  alphag[idx] = al;
  c0g[idx]    = 1.f - lam;
  c1g[idx]    = lam * al;
}

// ---------------------------------------------------------------------------
// f64 inclusive cumsum of dt over L, per group.  grid=4 (g), block=256.
// ---------------------------------------------------------------------------
__global__ __launch_bounds__(256)
void cumsum_dt_kernel(const float* __restrict__ dtg, float* __restrict__ cumdt)
{
  const int g = blockIdx.x;
  const int t = threadIdx.x;
  constexpr int PER = L_SEQ / 256;  // 8
  __shared__ double ps[256];
  float loc[PER];
  double s = 0.0;
  int l0 = t * PER;
  for (int i = 0; i < PER; ++i) {
    loc[i] = dtg[(l0 + i) * 4 + g];
    s += (double)loc[i];
  }
  ps[t] = s;
  __syncthreads();
  for (int off = 1; off < 256; off <<= 1) {
    double v = (t >= off) ? ps[t - off] : 0.0;
    __syncthreads();
    ps[t] += v;
    __syncthreads();
  }
  double c = ps[t] - s;  // exclusive prefix
  for (int i = 0; i < PER; ++i) {
    c += (double)loc[i];
    cumdt[(l0 + i) * 4 + g] = (float)c;
  }
}

// ---------------------------------------------------------------------------
// Per-token: silu(xp) -> xs ; rms+bias+rope for B/C (group level).
// ---------------------------------------------------------------------------
__global__ __launch_bounds__(256)
void pertoken_kernel(const float* __restrict__ proj,
                     const float* __restrict__ cumdt,
                     const float* __restrict__ theta_log,
                     const float* __restrict__ norm_B_w,
                     const float* __restrict__ norm_C_w,
                     const float* __restrict__ bias_B,
                     const float* __restrict__ bias_C,
                     float* __restrict__ xs,
                     float* __restrict__ Brot,
                     float* __restrict__ Crot)
{
  const int l = blockIdx.x;
  const int t = threadIdx.x;
  const size_t prow = (size_t)l * DPROJ;

  for (int i = t; i < 1024; i += 256) {
    float x = proj[prow + OFF_X + i];
    xs[(size_t)l * 1024 + i] = x / (1.f + expf(-x));
  }

  const int g = t >> 6;
  const int e = t & 63;
  float bv = proj[prow + OFF_B + t];
  float cv = proj[prow + OFF_C + t];
  float ssb = bv * bv, ssc = cv * cv;
#pragma unroll
  for (int m = 1; m <= 32; m <<= 1) {
    ssb += __shfl_xor(ssb, m, 64);
    ssc += __shfl_xor(ssc, m, 64);
  }
  float nb = bv * rsqrtf(ssb * (1.f / 64.f) + 1e-5f) * norm_B_w[e] + bias_B[t];
  float nc = cv * rsqrtf(ssc * (1.f / 64.f) + 1e-5f) * norm_C_w[e] + bias_C[t];

  float ang = expf(theta_log[g * 16 + (e >> 2)]) * cumdt[l * 4 + g];
  float ca, sa;
  sincosf(ang, &sa, &ca);   // sincosf writes SIN to 1st ptr, COS to 2nd
  float nb2 = __shfl_xor(nb, 2, 64);
  float nc2 = __shfl_xor(nc, 2, 64);
  bool isre = ((e >> 1) & 1) == 0;
  float Bo, Co;
  if (isre) {
    Bo = nb * ca + nb2 * sa;   // theta = -ang
    Co = nc * ca - nc2 * sa;   // theta = +ang
  } else {
    Bo = nb * ca - nb2 * sa;
    Co = nc * ca + nc2 * sa;
  }
  Brot[(size_t)l * 256 + t] = Bo;
  Crot[(size_t)l * 256 + t] = Co;
}

// ---------------------------------------------------------------------------
// Scan (new structure): lane = p, per-thread state H[n=0..31] + uprev[n].
// grid = (NCH, G), block = 256 (4 waves = 4 heads of group g).
// B (dt-folded) and C staged in LDS, read as wave-uniform broadcast b128.
// WITH_Y=false: pass A (from zero state, write hlast).
// WITH_Y=true : pass C (from hstates, write y128; no hlast).
// ---------------------------------------------------------------------------
template<bool WITH_Y>
__global__ __launch_bounds__(256)
void scan_chunk(const float* __restrict__ Brot, const float* __restrict__ Crot,
                const float* __restrict__ xup,
                const float* __restrict__ dtg, const float* __restrict__ alphag,
                const float* __restrict__ c0g, const float* __restrict__ c1g,
                const float* __restrict__ hstates_in,
                float* __restrict__ hlast_out, float* __restrict__ y128)
{
  const int c   = blockIdx.x;
  const int g   = blockIdx.y;
  const int wid = threadIdx.x >> 6;
  const int p   = threadIdx.x & 63;
  const int h   = g * 4 + wid;
  const int l0  = c * SCHUNK;

  __shared__ float Bs[SCHUNK][64];
  __shared__ float Cs[SCHUNK][64];
  __shared__ float als[SCHUNK], c0s[SCHUNK], c1s[SCHUNK];

  for (int i = threadIdx.x; i < SCHUNK * 64; i += 256) {
    int l = i >> 6, e = i & 63;
    float dt = dtg[(l0 + l) * 4 + g];
    Bs[l][e] = dt * Brot[(size_t)(l0 + l) * 256 + g * 64 + e];
    if (WITH_Y) Cs[l][e] = Crot[(size_t)(l0 + l) * 256 + g * 64 + e];
  }
  if (threadIdx.x < SCHUNK) {
    int l = threadIdx.x;
    als[l] = alphag[(l0 + l) * 4 + g];
    c0s[l] = c0g[(l0 + l) * 4 + g];
    c1s[l] = c1g[(l0 + l) * 4 + g];
  }
  __syncthreads();

  float H[32], up[32];
  if (WITH_Y) {
    const float* hs = &hstates_in[(((size_t)c * 16 + h) * 64 + p) * 32];
#pragma unroll
    for (int q = 0; q < 8; ++q) {
      float4 v = *reinterpret_cast<const float4*>(hs + 4 * q);
      H[4 * q] = v.x; H[4 * q + 1] = v.y; H[4 * q + 2] = v.z; H[4 * q + 3] = v.w;
    }
  } else {
#pragma unroll
    for (int n = 0; n < 32; ++n) H[n] = 0.f;
  }

  if (c > 0) {
    const int lm = l0 - 1;
    const float dtm = dtg[lm * 4 + g];
    float2 X = *reinterpret_cast<const float2*>(&xup[((size_t)lm * 16 + h) * 128 + 2 * p]);
    float x0 = dtm * X.x, x1 = dtm * X.y;
#pragma unroll
    for (int n = 0; n < 32; ++n) {
      float2 Bv = *reinterpret_cast<const float2*>(&Brot[(size_t)lm * 256 + g * 64 + 2 * n]);
      up[n] = Bv.x * x0 + Bv.y * x1;
    }
  } else {
#pragma unroll
    for (int n = 0; n < 32; ++n) up[n] = 0.f;
  }

  for (int l = 0; l < SCHUNK; ++l) {
    float2 X = *reinterpret_cast<const float2*>(
        &xup[((size_t)(l0 + l) * 16 + h) * 128 + 2 * p]);
    const float al = als[l], cc0 = c0s[l], cc1 = c1s[l];
    float y0 = 0.f, y1 = 0.f;
#pragma unroll
    for (int n2 = 0; n2 < 16; ++n2) {
      float4 Bv = *reinterpret_cast<const float4*>(&Bs[l][4 * n2]);
      float uin0 = Bv.x * X.x + Bv.y * X.y;       // n = 2*n2
      float uin1 = Bv.z * X.x + Bv.w * X.y;       // n = 2*n2+1
      float ue0 = cc0 * uin0 + cc1 * up[2 * n2];
      float ue1 = cc0 * uin1 + cc1 * up[2 * n2 + 1];
      H[2 * n2]     = al * H[2 * n2]     + ue0;
      H[2 * n2 + 1] = al * H[2 * n2 + 1] + ue1;
      up[2 * n2] = uin0; up[2 * n2 + 1] = uin1;
      if (WITH_Y) {
        float4 Cv = *reinterpret_cast<const float4*>(&Cs[l][4 * n2]);
        y0 = fmaf(H[2 * n2], Cv.x, fmaf(H[2 * n2 + 1], Cv.z, y0));
        y1 = fmaf(H[2 * n2], Cv.y, fmaf(H[2 * n2 + 1], Cv.w, y1));
      }
    }
    if (WITH_Y) {
      *reinterpret_cast<float2*>(&y128[((size_t)(l0 + l) * 16 + h) * 128 + 2 * p]) =
          make_float2(y0, y1);
    }
  }

  if (!WITH_Y) {
    float* hl = &hlast_out[(((size_t)c * 16 + h) * 64 + p) * 32];
#pragma unroll
    for (int q = 0; q < 8; ++q)
      *reinterpret_cast<float4*>(hl + 4 * q) =
          make_float4(H[4 * q], H[4 * q + 1], H[4 * q + 2], H[4 * q + 3]);
  }
}

// ---------------------------------------------------------------------------
// Scan pass B: cross-chunk combine -> h_states (state entering each chunk).
// ---------------------------------------------------------------------------
__global__ __launch_bounds__(256)
void scan_passB(const float* __restrict__ hlast, const float* __restrict__ cumdt,
                const float* __restrict__ A_log, float* __restrict__ hstates)
{
  int idx = blockIdx.x * 256 + threadIdx.x;   // H * P * N = 32768
  int h = idx >> 11;
  int rem = idx & 2047;                       // p*32 + n
  int g = h >> 2;
  float Ag = -expf(A_log[g]);
  float s = 0.f;
  for (int c = 0; c < NCH; ++c) {
    hstates[((size_t)c * 16 + h) * 2048 + rem] = s;
    float sd = cumdt[(c * SCHUNK + SCHUNK - 1) * 4 + g]
             - (c > 0 ? cumdt[(c * SCHUNK - 1) * 4 + g] : 0.f);
    float dec = expf(Ag * sd);
    s = s * dec + hlast[((size_t)c * 16 + h) * 2048 + rem];
  }
}

// ---------------------------------------------------------------------------
// Fuse: yg = (yd + D[h]*xs) * silu(z), written in place into proj's z region.
// ---------------------------------------------------------------------------
__global__ __launch_bounds__(256)
void fuse_gate_kernel(const float* __restrict__ yd, const float* __restrict__ xs,
                      const float* __restrict__ Dv, float* __restrict__ proj)
{
  int idx = blockIdx.x * 256 + threadIdx.x;   // L * 1024
  int l = idx >> 10, m = idx & 1023, h = m >> 6;
  float v = yd[((size_t)l * 16 + h) * 64 + (m & 63)] + Dv[h] * xs[idx];
  float z = proj[(size_t)l * DPROJ + m];
  float sz = z / (1.f + expf(-z));
  proj[(size_t)l * DPROJ + m] = v * sz;
}

}  // namespace

extern "C" void kernel_launch(void* const* d_in, const int* in_sizes, int n_in,
                              void* d_out, int out_size, void* d_ws, size_t ws_size,
                              hipStream_t stream)
{
  const float* u         = (const float*)d_in[0];
  const float* W_in      = (const float*)d_in[1];
  const float* b_in      = (const float*)d_in[2];
  const float* W_xup     = (const float*)d_in[3];
  const float* W_ydown   = (const float*)d_in[4];
  const float* A_log     = (const float*)d_in[5];
  const float* theta_log = (const float*)d_in[6];
  const float* Dvec      = (const float*)d_in[7];
  const float* norm_B_w  = (const float*)d_in[8];
  const float* norm_C_w  = (const float*)d_in[9];
  const float* bias_B    = (const float*)d_in[10];
  const float* bias_C    = (const float*)d_in[11];
  const float* W_out     = (const float*)d_in[12];
  float* out = (float*)d_out;

  // Workspace carve (f32 counts). hlast aliases y128 (dead before passC's
  // y-writes), hstates aliases yd (dead before gemm9 writes yd) — all
  // stream-ordered, so no hazards.
  float* proj    = (float*)d_ws;                    // 2048*2568
  float* xs      = proj    + (size_t)L_SEQ * DPROJ; // 2048*1024
  float* dtg     = xs      + (size_t)L_SEQ * 1024;  // 2048*4
  float* alphag  = dtg     + L_SEQ * 4;
  float* c0g     = alphag  + L_SEQ * 4;
  float* c1g     = c0g     + L_SEQ * 4;
  float* cumdt   = c1g     + L_SEQ * 4;
  float* Brot    = cumdt   + L_SEQ * 4;             // 2048*256
  float* Crot    = Brot    + (size_t)L_SEQ * 256;
  float* xup     = Crot    + (size_t)L_SEQ * 256;   // 32768*128
  float* y128    = xup     + (size_t)32768 * 128;   // 32768*128
  float* yd      = y128    + (size_t)32768 * 128;   // 32768*64
  float* hlast   = y128;                            // NCH*16*2048 = 2.10M <= 4.19M
  float* hstates = yd;                              // NCH*16*2048 = 2.10M == 2.10M

  // 1. proj = u @ W_in^T + b_in        (2048 x 2568, K=512)
  gemm_abt<128, 128, 8, 8, 8><<<dim3(16, 21), 256, 0, stream>>>(
      u, 512, W_in, 512, b_in, proj, DPROJ, L_SEQ, DPROJ, 512);

  // 2. dt / lam / alpha coefficients
  dtlam_kernel<<<dim3(32), 256, 0, stream>>>(proj, A_log, dtg, alphag, c0g, c1g);

  // 3. f64 cumsum of dt per group
  cumsum_dt_kernel<<<dim3(4), 256, 0, stream>>>(dtg, cumdt);

  // 4. per-token: silu(xp), rms+bias+rope -> Brot/Crot
  pertoken_kernel<<<dim3(L_SEQ), 256, 0, stream>>>(
      proj, cumdt, theta_log, norm_B_w, norm_C_w, bias_B, bias_C, xs, Brot, Crot);

  // 5. x_up = xs(32768x64) @ W_xup^T(64x128)
  gemm_abt<128, 128, 8, 8, 8><<<dim3(256, 1), 256, 0, stream>>>(
      xs, 64, W_xup, 64, nullptr, xup, 128, 32768, 128, 64);

  // 6-8. chunked scan (state-in-registers formulation)
  scan_chunk<false><<<dim3(NCH, 4), 256, 0, stream>>>(
      Brot, Crot, xup, dtg, alphag, c0g, c1g, nullptr, hlast, nullptr);
  scan_passB<<<dim3(128), 256, 0, stream>>>(hlast, cumdt, A_log, hstates);
  scan_chunk<true><<<dim3(NCH, 4), 256, 0, stream>>>(
      Brot, Crot, xup, dtg, alphag, c0g, c1g, hstates, nullptr, y128);

  // 9. yd = y128(32768x128) @ W_ydown^T(128x64)
  gemm_abt<128, 64, 8, 8, 4><<<dim3(256, 1), 256, 0, stream>>>(
      y128, 128, W_ydown, 128, nullptr, yd, 64, 32768, 64, 128);

  // 10. gate: yg = (yd + D*xs) * silu(z), in place into proj[:, 0:1024]
  fuse_gate_kernel<<<dim3(8192), 256, 0, stream>>>(yd, xs, Dvec, proj);

  // 11. out = yg(2048x1024) @ W_out^T(1024->512)
  gemm_abt<64, 64, 8, 4, 4><<<dim3(32, 8), 256, 0, stream>>>(
      proj, DPROJ, W_out, 1024, nullptr, out, 512, L_SEQ, 512, 1024);
}